// Round 12
// baseline (103.660 us; speedup 1.0000x reference)
//
#include <hip/hip_runtime.h>
#include <hip/hip_bf16.h>

typedef __attribute__((ext_vector_type(8))) short bf16x8;
typedef __attribute__((ext_vector_type(4))) float f32x4;
typedef __attribute__((ext_vector_type(4))) unsigned short u16x4;
typedef unsigned short u16;

#define BATCH 100000
#define EPE 200000

// ---- workspace layout (bytes), ~27.6 MB, no aliasing ----
#define OFF_AP    ((size_t)0)          // u16 [1024*1024]
#define OFF_ATP   ((size_t)2097152)    // u16 [1024*1024]
#define OFF_SP    ((size_t)4194304)    // u16 [1024*1024]
#define OFF_T1    ((size_t)6291456)    // u16 [2048*2048]
#define OFF_GNS   ((size_t)14680064)   // u16 [1024*1024]  bf16 Gamma (src rows)
#define OFF_GNDT  ((size_t)16777216)   // u16 [1024*1024]  bf16 Gamma^T (dst rows)
#define OFF_W1AT  ((size_t)18874368)   // u16 [256*1024]
#define OFF_W1BT  ((size_t)19398656)   // u16 [256*1024]
#define OFF_W2T   ((size_t)19922944)   // u16 [128*256]
#define OFF_HID   ((size_t)19988480)   // u16 [2048*256]
#define OFF_NEP   ((size_t)21037056)   // u16 [2048*128]
#define OFF_CEP   ((size_t)21561344)   // u16 [2048*128]
#define OFF_HSRC  ((size_t)22085632)   // u16 [1024*256]
#define OFF_HDST  ((size_t)22609920)   // u16 [1024*256]
#define OFF_T2    ((size_t)23134208)   // f32 [1024*1024]
#define OFF_ROWP  ((size_t)27328512)   // f32 [32*1024] per-coltile row sumsq partials
#define OFF_COLP  ((size_t)27459584)   // f32 [32*1024] per-rowtile col sumsq partials
#define OFF_DEGS  ((size_t)27590656)   // f32 [1024]
#define OFF_DEGD  ((size_t)27594752)   // f32 [1024]
#define OFF_PART  ((size_t)27598848)   // f32 [391]

__device__ __forceinline__ u16 f2b(float f) {
  union { float f; unsigned u; } v; v.f = f;
  unsigned r = v.u + 0x7fffu + ((v.u >> 16) & 1u);
  return (u16)(r >> 16);
}
__device__ __forceinline__ float b2f(u16 h) {
  union { unsigned u; float f; } v; v.u = ((unsigned)h) << 16;
  return v.f;
}

#define AS1C(p) ((const __attribute__((address_space(1))) void*)(p))
#define AS3(p)  ((__attribute__((address_space(3))) void*)(p))

// ---------------- fused prep: all packs + degrees, vectorized (proven R6) ----------------
__global__ __launch_bounds__(256) void prep(const float* __restrict__ adj,
    const float* __restrict__ W1, const float* __restrict__ W2,
    const float* __restrict__ ne, const float* __restrict__ ce,
    u16* __restrict__ Ap, u16* __restrict__ ATp,
    u16* __restrict__ W1At, u16* __restrict__ W1Bt, u16* __restrict__ w2t,
    u16* __restrict__ nep, u16* __restrict__ cep,
    u16* __restrict__ hsrcp, u16* __restrict__ hdstp,
    float* __restrict__ degd, float* __restrict__ degs) {
  __shared__ float tile[64][65];
  __shared__ float redf[256];
  __shared__ float4 red4[8][32];
  int b = blockIdx.x;
  int t = threadIdx.x;
  int tx = t & 63, ty = t >> 6;
  if (b < 256) {
    int tr = b >> 4, tc = b & 15;
    int l16 = t & 15, rq = t >> 4;
    #pragma unroll
    for (int p = 0; p < 4; p++) {
      int r = p * 16 + rq;
      int gr = tr * 64 + r, gc0 = tc * 64 + l16 * 4;
      float4 v = {0.f, 0.f, 0.f, 0.f};
      if (gr < 1000 && gc0 < 1000) v = *(const float4*)&adj[(size_t)gr * 2000 + 1000 + gc0];
      u16x4 pk = {f2b(v.x), f2b(v.y), f2b(v.z), f2b(v.w)};
      *(u16x4*)&Ap[(size_t)gr * 1024 + gc0] = pk;
      tile[r][l16 * 4 + 0] = v.x;
      tile[r][l16 * 4 + 1] = v.y;
      tile[r][l16 * 4 + 2] = v.z;
      tile[r][l16 * 4 + 3] = v.w;
    }
    __syncthreads();
    #pragma unroll
    for (int p = 0; p < 16; p++) {
      int r = p * 4 + ty;
      ATp[(size_t)(tc * 64 + r) * 1024 + tr * 64 + tx] = f2b(tile[tx][r]);
    }
  } else if (b < 384) {
    int b2 = b - 256;
    int half = b2 >> 6, rem = b2 & 63;
    int jt = rem >> 2, ht = rem & 3;
    #pragma unroll
    for (int p = 0; p < 16; p++) {
      int r = p * 4 + ty;
      int j = jt * 64 + r;
      tile[r][tx] = (j < 1000) ? W1[(size_t)(half * 1000 + j) * 256 + ht * 64 + tx] : 0.f;
    }
    __syncthreads();
    u16* outp = half ? W1Bt : W1At;
    #pragma unroll
    for (int p = 0; p < 16; p++) {
      int r = p * 4 + ty;
      outp[(size_t)(ht * 64 + r) * 1024 + jt * 64 + tx] = f2b(tile[tx][r]);
    }
  } else if (b < 392) {
    int b3 = b - 384;
    int dt = b3 >> 2, kt = b3 & 3;
    #pragma unroll
    for (int p = 0; p < 16; p++) {
      int r = p * 4 + ty;
      tile[r][tx] = W2[(size_t)(kt * 64 + r) * 128 + dt * 64 + tx];
    }
    __syncthreads();
    #pragma unroll
    for (int p = 0; p < 16; p++) {
      int r = p * 4 + ty;
      w2t[(size_t)(dt * 64 + r) * 256 + kt * 64 + tx] = f2b(tile[tx][r]);
    }
  } else if (b < 648) {
    int idx = (b - 392) * 256 + t;
    int i = idx >> 5, d4 = (idx & 31) * 4;
    float4 nv4 = {0.f, 0.f, 0.f, 0.f}, cv4 = {0.f, 0.f, 0.f, 0.f};
    if (i < 2000) {
      nv4 = *(const float4*)&ne[(size_t)i * 128 + d4];
      cv4 = *(const float4*)&ce[(size_t)i * 128 + d4];
    }
    u16x4 nb = {f2b(nv4.x), f2b(nv4.y), f2b(nv4.z), f2b(nv4.w)};
    u16x4 cb = {f2b(cv4.x), f2b(cv4.y), f2b(cv4.z), f2b(cv4.w)};
    u16x4 zz = {0, 0, 0, 0};
    *(u16x4*)&nep[(size_t)i * 128 + d4] = nb;
    *(u16x4*)&cep[(size_t)i * 128 + d4] = cb;
    if (i < 1000)                   *(u16x4*)&hsrcp[(size_t)i * 256 + d4] = nb;
    else if (i < 1024)              *(u16x4*)&hsrcp[(size_t)i * 256 + d4] = zz;
    if (i >= 1000 && i < 2000)      *(u16x4*)&hdstp[(size_t)(i - 1000) * 256 + d4] = nb;
    else if (i >= 2000 && i < 2024) *(u16x4*)&hdstp[(size_t)(i - 1000) * 256 + d4] = zz;
  } else if (b < 656) {
    int jb = b - 648;
    int cx = t & 31, ry = t >> 5;
    int j4 = jb * 128 + cx * 4;
    float4 s = {0.f, 0.f, 0.f, 0.f};
    if (j4 < 1000)
      for (int i = ry; i < 1000; i += 8) {
        float4 v = *(const float4*)&adj[(size_t)i * 2000 + 1000 + j4];
        s.x += v.x; s.y += v.y; s.z += v.z; s.w += v.w;
      }
    red4[ry][cx] = s;
    __syncthreads();
    if (ry == 0) {
      float4 tot = {0.f, 0.f, 0.f, 0.f};
      #pragma unroll
      for (int k = 0; k < 8; k++) {
        float4 v = red4[k][cx];
        tot.x += v.x; tot.y += v.y; tot.z += v.z; tot.w += v.w;
      }
      *(float4*)&degd[j4] = tot;
    }
  } else {
    int ib = b - 656;
    int r = t >> 3, c8 = t & 7;
    int i = ib * 32 + r;
    float s = 0.f;
    if (i < 1000)
      for (int k4 = c8 * 4; k4 < 1000; k4 += 32) {
        float4 v = *(const float4*)&adj[(size_t)i * 2000 + 1000 + k4];
        s += v.x + v.y + v.z + v.w;
      }
    redf[t] = s;
    __syncthreads();
    if (c8 == 0) {
      float tot = 0.f;
      #pragma unroll
      for (int k = 0; k < 8; k++) tot += redf[r * 8 + k];
      degs[i] = (i < 1000) ? tot : 0.f;
    }
  }
}

// ---------------- 32x32-tile bf16 MFMA core, 2-phase dbuf, XOR-swizzled LDS ----------------
__device__ __forceinline__ f32x4 gemm_core32(const u16* A, const u16* BT,
    int K, int lda, int ldbt, int brow, int bcol, u16* As, u16* Bs) {
  const int t = threadIdx.x;
  const int w = t >> 6, lane = t & 63;
  const int wr = w >> 1, wc = w & 1;
  const int r16 = lane & 15, kg = lane >> 4;
  const int row = t >> 3;
  const int csrc = (t & 7) ^ (row & 7);          // pre-swizzled source chunk
  f32x4 acc = {0.f, 0.f, 0.f, 0.f};
  const int nst = K >> 6;
  {
    const u16* ga = A + (size_t)(brow + row) * lda + csrc * 8;
    __builtin_amdgcn_global_load_lds(AS1C(ga), AS3(As + t * 8), 16, 0, 0);
    const u16* gb = BT + (size_t)(bcol + row) * ldbt + csrc * 8;
    __builtin_amdgcn_global_load_lds(AS1C(gb), AS3(Bs + t * 8), 16, 0, 0);
  }
  const int Ra = wr * 16 + r16;
  const int Rb = wc * 16 + r16;
  int cur = 0;
  for (int s = 0; s < nst; ++s) {
    __syncthreads();
    if (s + 1 < nst) {
      int k0 = (s + 1) << 6, nb = cur ^ 1;
      const u16* ga = A + (size_t)(brow + row) * lda + k0 + csrc * 8;
      __builtin_amdgcn_global_load_lds(AS1C(ga), AS3(As + nb * 2048 + t * 8), 16, 0, 0);
      const u16* gb = BT + (size_t)(bcol + row) * ldbt + k0 + csrc * 8;
      __builtin_amdgcn_global_load_lds(AS1C(gb), AS3(Bs + nb * 2048 + t * 8), 16, 0, 0);
    }
    const u16* Asc = As + cur * 2048;
    const u16* Bsc = Bs + cur * 2048;
    #pragma unroll
    for (int kk = 0; kk < 2; ++kk) {
      int g = kk * 4 + kg;
      bf16x8 af = *(const bf16x8*)&Asc[Ra * 64 + ((g ^ (Ra & 7)) * 8)];
      bf16x8 bf_ = *(const bf16x8*)&Bsc[Rb * 64 + ((g ^ (Rb & 7)) * 8)];
      acc = __builtin_amdgcn_mfma_f32_16x16x32_bf16(af, bf_, acc, 0, 0, 0);
    }
    cur ^= 1;
  }
  return acc;
}

// ---------------- K=128 single-shot core: stage both halves, one barrier, 4 MFMA ----------------
__device__ __forceinline__ f32x4 gemm_core32_k128(const u16* A, const u16* BT,
    int lda, int ldbt, int brow, int bcol, u16* As, u16* Bs) {
  const int t = threadIdx.x;
  const int w = t >> 6, lane = t & 63;
  const int wr = w >> 1, wc = w & 1;
  const int r16 = lane & 15, kg = lane >> 4;
  const int row = t >> 3;
  const int csrc = (t & 7) ^ (row & 7);
  #pragma unroll
  for (int h = 0; h < 2; h++) {
    const u16* ga = A + (size_t)(brow + row) * lda + h * 64 + csrc * 8;
    __builtin_amdgcn_global_load_lds(AS1C(ga), AS3(As + h * 2048 + t * 8), 16, 0, 0);
    const u16* gb = BT + (size_t)(bcol + row) * ldbt + h * 64 + csrc * 8;
    __builtin_amdgcn_global_load_lds(AS1C(gb), AS3(Bs + h * 2048 + t * 8), 16, 0, 0);
  }
  __syncthreads();
  const int Ra = wr * 16 + r16, Rb = wc * 16 + r16;
  f32x4 acc = {0.f, 0.f, 0.f, 0.f};
  #pragma unroll
  for (int h = 0; h < 2; h++) {
    const u16* Asc = As + h * 2048;
    const u16* Bsc = Bs + h * 2048;
    #pragma unroll
    for (int kk = 0; kk < 2; ++kk) {
      int g = kk * 4 + kg;
      bf16x8 af = *(const bf16x8*)&Asc[Ra * 64 + ((g ^ (Ra & 7)) * 8)];
      bf16x8 bf_ = *(const bf16x8*)&Bsc[Rb * 64 + ((g ^ (Rb & 7)) * 8)];
      acc = __builtin_amdgcn_mfma_f32_16x16x32_bf16(af, bf_, acc, 0, 0, 0);
    }
  }
  return acc;
}

// ---------------- mega1: symmetric S = A A^T (528, FIRST) + T1 = ne@ce^T (4096, single-shot) ----
__global__ __launch_bounds__(256) void mega1(const u16* __restrict__ nep, const u16* __restrict__ cep,
    const u16* __restrict__ Ap, u16* __restrict__ T1, u16* __restrict__ Sp) {
  __shared__ u16 As[2 * 2048];
  __shared__ u16 Bs[2 * 2048];
  __shared__ u16 mir[32 * 33];
  int b = blockIdx.x;
  const int t = threadIdx.x;
  const int w = t >> 6, lane = t & 63;
  const int wr = w >> 1, wc = w & 1;
  const int r16 = lane & 15, kg = lane >> 4;
  if (b < 528) {                            // S jobs first (K=1024, long)
    int s = b;
    int bi = (int)((sqrtf(8.f * s + 1.f) - 1.f) * 0.5f);
    while (bi * (bi + 1) / 2 > s) bi--;
    while ((bi + 1) * (bi + 2) / 2 <= s) bi++;
    int bj = s - bi * (bi + 1) / 2;
    int brow = bi * 32, bcol = bj * 32;
    f32x4 acc = gemm_core32(Ap, Ap, 1024, 1024, 1024, brow, bcol, As, Bs);
    #pragma unroll
    for (int j = 0; j < 4; j++) {
      int lr = wr * 16 + kg * 4 + j, lc = wc * 16 + r16;
      u16 v = f2b(acc[j]);
      Sp[(size_t)(brow + lr) * 1024 + bcol + lc] = v;
      mir[lr * 33 + lc] = v;
    }
    __syncthreads();
    #pragma unroll
    for (int p = 0; p < 4; p++) {
      int idx = p * 256 + t, rr = idx >> 5, cc = idx & 31;
      Sp[(size_t)(bcol + rr) * 1024 + brow + cc] = mir[cc * 33 + rr];
    }
  } else {                                  // T1 jobs (K=128, single-shot staging)
    int b2 = b - 528;
    int brow = (b2 >> 6) * 32, bcol = (b2 & 63) * 32;
    f32x4 acc = gemm_core32_k128(nep, cep, 128, 128, brow, bcol, As, Bs);
    #pragma unroll
    for (int j = 0; j < 4; j++) {
      int row = brow + wr * 16 + kg * 4 + j, col = bcol + wc * 16 + r16;
      T1[(size_t)row * 2048 + col] = f2b(acc[j]);
    }
  }
}

// ---------------- mega2: skipgram gather FIRST (391) + G gemm -> bf16 + norm partials (1024) ----
__global__ __launch_bounds__(256) void mega2(const u16* __restrict__ Sp, const u16* __restrict__ ATp,
    const u16* __restrict__ Ap, const float* __restrict__ degs, const float* __restrict__ degd,
    u16* __restrict__ Gns, u16* __restrict__ Gndt,
    float* __restrict__ rowp, float* __restrict__ colp,
    const u16* __restrict__ T1, const int* __restrict__ pu, const int* __restrict__ pv,
    const int* __restrict__ nv, float* __restrict__ partial) {
  __shared__ u16 As[2 * 2048];
  __shared__ u16 Bs[2 * 2048];
  __shared__ float gtile[32 * 33];
  __shared__ float red[256];
  int b = blockIdx.x;
  const int t = threadIdx.x;
  if (b < 391) {                            // skipgram gather (latency-bound, issue early)
    int s = b * 256 + t;
    float loss = 0.f;
    if (s < BATCH) {
      const u16* trow = T1 + (size_t)pu[s] * 2048;
      const int* nvb = nv + (size_t)s * 5;
      float ap = b2f(trow[pv[s]]);
      ap = fminf(fmaxf(ap, -10.f), 10.f); loss = log1pf(expf(-ap));
      #pragma unroll
      for (int k = 0; k < 5; k++) {
        float a = b2f(trow[nvb[k]]);
        a = fminf(fmaxf(a, -10.f), 10.f);
        loss += log1pf(expf(a));
      }
    }
    red[t] = loss;
    __syncthreads();
    for (int off = 128; off > 0; off >>= 1) {
      if (t < off) red[t] += red[t + off];
      __syncthreads();
    }
    if (t == 0) partial[b] = red[0];
    return;
  }
  const int w = t >> 6, lane = t & 63;
  const int wr = w >> 1, wc = w & 1;
  const int r16 = lane & 15, kg = lane >> 4;
  int b2 = b - 391;
  int brow = (b2 >> 5) * 32, bcol = (b2 & 31) * 32;
  f32x4 acc = gemm_core32(Sp, ATp, 1024, 1024, 1024, brow, bcol, As, Bs);
  #pragma unroll
  for (int j = 0; j < 4; j++) {
    int lr = wr * 16 + kg * 4 + j, lc = wc * 16 + r16;
    int row = brow + lr, col = bcol + lc;
    float a = b2f(Ap[(size_t)row * 1024 + col]);
    float p2 = degs[row] * degd[col];
    float g = (p2 > 0.f) ? (acc[j] * a) / p2 : 0.f;
    Gns[(size_t)row * 1024 + col] = f2b(g);
    gtile[lr * 33 + lc] = g;
  }
  __syncthreads();
  // transposed bf16 write (coalesced)
  #pragma unroll
  for (int p = 0; p < 4; p++) {
    int idx = p * 256 + t, rr = idx >> 5, cc = idx & 31;
    Gndt[(size_t)(bcol + rr) * 1024 + brow + cc] = f2b(gtile[cc * 33 + rr]);
  }
  // deterministic norm partials: one writer per slot
  if (t < 32) {
    float s = 0.f;
    #pragma unroll
    for (int k = 0; k < 32; k++) { float g = gtile[t * 33 + k]; s += g * g; }
    rowp[(size_t)(bcol >> 5) * 1024 + brow + t] = s;
  } else if (t < 64) {
    int c = t - 32;
    float s = 0.f;
    #pragma unroll
    for (int k = 0; k < 32; k++) { float g = gtile[k * 33 + c]; s += g * g; }
    colp[(size_t)(brow >> 5) * 1024 + bcol + c] = s;
  }
}

// ---------------- hid = tanh((Gamma @ W1)/r + b1): 512 blocks (z = b>>8) ----------------
__global__ __launch_bounds__(256) void gemm_hid(const u16* __restrict__ Gns, const u16* __restrict__ W1Bt,
    const u16* __restrict__ Gndt, const u16* __restrict__ W1At,
    const float* __restrict__ rowp, const float* __restrict__ colp,
    const float* __restrict__ b1, u16* __restrict__ hid) {
  __shared__ u16 As[2 * 2048];
  __shared__ u16 Bs[2 * 2048];
  __shared__ float invr[32];
  const int t = threadIdx.x;
  const int w = t >> 6, lane = t & 63;
  const int wr = w >> 1, wc = w & 1;
  const int r16 = lane & 15, kg = lane >> 4;
  int b = blockIdx.x;
  int z = b >> 8, rem = b & 255;
  int brow = (rem & 31) * 32, bcol = (rem >> 5) * 32;
  if (t < 32) {
    const float* pp = z ? colp : rowp;
    float s = 0.f;
    #pragma unroll
    for (int k = 0; k < 32; k++) s += pp[(size_t)k * 1024 + brow + t];
    invr[t] = 1.0f / fmaxf(sqrtf(s), 1e-12f);
  }
  const u16* Au = z ? Gndt : Gns;
  const u16* Bu = z ? W1At : W1Bt;
  f32x4 acc = gemm_core32(Au, Bu, 1024, 1024, 1024, brow, bcol, As, Bs);
  #pragma unroll
  for (int j = 0; j < 4; j++) {
    int lr = wr * 16 + kg * 4 + j;
    int row = brow + lr;
    int col = bcol + wc * 16 + r16;
    hid[(size_t)((z << 10) + row) * 256 + col] = f2b(tanhf(acc[j] * invr[lr] + b1[col]));
  }
}

// ---------------- h[:,128:] = hid @ W2 + b2 (256 blocks) ----------------
__global__ __launch_bounds__(256) void gemm_w2(const u16* __restrict__ hid, const u16* __restrict__ w2t,
    const float* __restrict__ b2, u16* __restrict__ hsrcp, u16* __restrict__ hdstp) {
  __shared__ u16 As[2 * 2048];
  __shared__ u16 Bs[2 * 2048];
  const int t = threadIdx.x;
  const int w = t >> 6, lane = t & 63;
  const int wr = w >> 1, wc = w & 1;
  const int r16 = lane & 15, kg = lane >> 4;
  int b = blockIdx.x;
  int brow = (b >> 2) * 32, bcol = (b & 3) * 32;
  f32x4 acc = gemm_core32(hid, w2t, 256, 256, 256, brow, bcol, As, Bs);
  #pragma unroll
  for (int j = 0; j < 4; j++) {
    int row = brow + wr * 16 + kg * 4 + j;
    int col = bcol + wc * 16 + r16;
    u16 hv = f2b(acc[j] + b2[col]);
    if (row < 1024) hsrcp[(size_t)row * 256 + 128 + col] = hv;
    else            hdstp[(size_t)(row - 1024) * 256 + 128 + col] = hv;
  }
}

// ---------------- T2 = h_src @ h_dst^T (1024 blocks) ----------------
__global__ __launch_bounds__(256) void gemm_t2(const u16* __restrict__ hsrcp, const u16* __restrict__ hdstp,
    float* __restrict__ T2) {
  __shared__ u16 As[2 * 2048];
  __shared__ u16 Bs[2 * 2048];
  const int t = threadIdx.x;
  const int w = t >> 6, lane = t & 63;
  const int wr = w >> 1, wc = w & 1;
  const int r16 = lane & 15, kg = lane >> 4;
  int b = blockIdx.x;
  int brow = (b >> 5) * 32, bcol = (b & 31) * 32;
  f32x4 acc = gemm_core32(hsrcp, hdstp, 256, 256, 256, brow, bcol, As, Bs);
  #pragma unroll
  for (int j = 0; j < 4; j++) {
    int row = brow + wr * 16 + kg * 4 + j;
    int col = bcol + wc * 16 + r16;
    T2[(size_t)row * 1024 + col] = acc[j];
  }
}

// ---------------- edge gather from T2 + final loss reduce (block 0) ----------------
__global__ __launch_bounds__(256) void edge_loss(const float* __restrict__ T2,
    const float* __restrict__ partial,
    const int* __restrict__ ps, const int* __restrict__ pd,
    const int* __restrict__ ns, const int* __restrict__ nd,
    float* __restrict__ out) {
  if (blockIdx.x == 0) {
    __shared__ float red[256];
    float s = 0.f;
    for (int i = threadIdx.x; i < 391; i += 256) s += partial[i];
    red[threadIdx.x] = s;
    __syncthreads();
    for (int off = 128; off > 0; off >>= 1) {
      if (threadIdx.x < off) red[threadIdx.x] += red[threadIdx.x + off];
      __syncthreads();
    }
    if (threadIdx.x == 0) out[0] = red[0] / (float)BATCH;
    return;
  }
  int e = (blockIdx.x - 1) * 256 + threadIdx.x;
  if (e >= 2 * EPE) return;
  int src, dst;
  if (e < EPE) { src = ps[e]; dst = pd[e]; }
  else         { src = ns[e - EPE]; dst = nd[e - EPE]; }
  out[1 + e] = T2[(size_t)src * 1024 + dst];
}

// ---------------- launch (7 kernels) ----------------
extern "C" void kernel_launch(void* const* d_in, const int* in_sizes, int n_in,
                              void* d_out, int out_size, void* d_ws, size_t ws_size,
                              hipStream_t stream) {
  const float* node_embed    = (const float*)d_in[0];
  const float* context_embed = (const float*)d_in[1];
  const float* adj           = (const float*)d_in[2];
  const float* W1            = (const float*)d_in[3];
  const float* b1            = (const float*)d_in[4];
  const float* W2            = (const float*)d_in[5];
  const float* b2            = (const float*)d_in[6];
  const int* pos_u   = (const int*)d_in[7];
  const int* pos_v   = (const int*)d_in[8];
  const int* neg_v   = (const int*)d_in[9];
  const int* pos_src = (const int*)d_in[10];
  const int* pos_dst = (const int*)d_in[11];
  const int* neg_src = (const int*)d_in[12];
  const int* neg_dst = (const int*)d_in[13];
  float* out = (float*)d_out;

  char* ws = (char*)d_ws;
  u16*   Ap    = (u16*)(ws + OFF_AP);
  u16*   ATp   = (u16*)(ws + OFF_ATP);
  u16*   Sp    = (u16*)(ws + OFF_SP);
  u16*   T1    = (u16*)(ws + OFF_T1);
  u16*   Gns   = (u16*)(ws + OFF_GNS);
  u16*   Gndt  = (u16*)(ws + OFF_GNDT);
  u16*   W1At  = (u16*)(ws + OFF_W1AT);
  u16*   W1Bt  = (u16*)(ws + OFF_W1BT);
  u16*   w2t   = (u16*)(ws + OFF_W2T);
  u16*   hid   = (u16*)(ws + OFF_HID);
  u16*   nep   = (u16*)(ws + OFF_NEP);
  u16*   cep   = (u16*)(ws + OFF_CEP);
  u16*   hsrcp = (u16*)(ws + OFF_HSRC);
  u16*   hdstp = (u16*)(ws + OFF_HDST);
  float* T2    = (float*)(ws + OFF_T2);
  float* rowp  = (float*)(ws + OFF_ROWP);
  float* colp  = (float*)(ws + OFF_COLP);
  float* degs  = (float*)(ws + OFF_DEGS);
  float* degd  = (float*)(ws + OFF_DEGD);
  float* part  = (float*)(ws + OFF_PART);

  // 1. packs + degrees
  prep<<<688, 256, 0, stream>>>(adj, W1, W2, node_embed, context_embed,
                                Ap, ATp, W1At, W1Bt, w2t, nep, cep, hsrcp, hdstp, degd, degs);
  // 2. S (528 long jobs first) + T1 (4096 single-shot jobs)
  mega1<<<4624, 256, 0, stream>>>(nep, cep, Ap, T1, Sp);
  // 3. skipgram gather (first, latency-bound) + G gemm -> bf16 Gamma/Gamma^T + norm partials
  mega2<<<1415, 256, 0, stream>>>(Sp, ATp, Ap, degs, degd, Gns, Gndt, rowp, colp,
                                  T1, pos_u, pos_v, neg_v, part);
  // 4. hid = tanh((Gamma @ W1)/r + b1)   [normalization folded in]
  gemm_hid<<<512, 256, 0, stream>>>(Gns, W1Bt, Gndt, W1At, rowp, colp, b1, hid);
  // 5. h[:,128:] = hid @ W2 + b2
  gemm_w2<<<256, 256, 0, stream>>>(hid, w2t, b2, hsrcp, hdstp);
  // 6. T2 = h_src @ h_dst^T
  gemm_t2<<<1024, 256, 0, stream>>>(hsrcp, hdstp, T2);
  // 7. edge gathers + final loss reduce (block 0)
  edge_loss<<<1564, 256, 0, stream>>>(T2, part, pos_src, pos_dst, neg_src, neg_dst, out);
}